// Round 11
// baseline (380.841 us; speedup 1.0000x reference)
//
#include <hip/hip_runtime.h>
#include <cmath>

#define FILT 11

typedef float v2f __attribute__((ext_vector_type(2)));

struct GW { float w[FILT]; };

// ---- order-preserving float<->uint encode for atomic min/max ----
__device__ __forceinline__ unsigned enc_f(float f) {
    unsigned u = __float_as_uint(f);
    return (u & 0x80000000u) ? ~u : (u | 0x80000000u);
}
__device__ __forceinline__ float dec_f(unsigned u) {
    return (u & 0x80000000u) ? __uint_as_float(u & 0x7FFFFFFFu)
                             : __uint_as_float(~u);
}

__global__ void init_acc(unsigned* ws) {
    int t = threadIdx.x;
    if (t == 0) { ws[0] = 0u; ws[1] = 0xFFFFFFFFu; }
    for (int i = 2 + t; i < 512; i += blockDim.x) ws[i] = 0u;  // float 0.0
}

__global__ void minmax_kernel(const float4* __restrict__ t, long n4, unsigned* mm) {
    unsigned mx = 0u, mn = 0xFFFFFFFFu;
    long stride = (long)gridDim.x * blockDim.x;
    for (long i = (long)blockIdx.x * blockDim.x + threadIdx.x; i < n4; i += stride) {
        float4 v = t[i];
        unsigned a = enc_f(v.x), b = enc_f(v.y), c = enc_f(v.z), d = enc_f(v.w);
        mx = max(mx, max(max(a, b), max(c, d)));
        mn = min(mn, min(min(a, b), min(c, d)));
    }
    for (int off = 32; off; off >>= 1) {
        mx = max(mx, (unsigned)__shfl_down((int)mx, off));
        mn = min(mn, (unsigned)__shfl_down((int)mn, off));
    }
    __shared__ unsigned smx[4], smn[4];
    int wid = threadIdx.x >> 6, lane = threadIdx.x & 63;
    if (lane == 0) { smx[wid] = mx; smn[wid] = mn; }
    __syncthreads();
    if (threadIdx.x == 0) {
        for (int i = 1; i < 4; i++) { mx = max(mx, smx[i]); mn = min(mn, smn[i]); }
        atomicMax(&mm[0], mx);
        atomicMin(&mm[1], mn);
    }
}

// Row-streaming fused SSIM + pool, DOUBLE-ROW steps (R10 core).
// Works with 256-thread (4-wave) or 1024-thread (16-wave) blocks.
__global__ __launch_bounds__(1024) void ssim_stream(
    const float* __restrict__ x, const float* __restrict__ y,
    int H, int W, int NC, int nstrips, int nb, int B,
    const unsigned* __restrict__ mm,
    float* __restrict__ cs_sum, float* __restrict__ ssim_sum, GW gw,
    float* __restrict__ poolx, float* __restrict__ pooly, int do_pool)
{
    __shared__ v2f ring[16][2][80];

    const int wv = threadIdx.x >> 6;
    const int lane = threadIdx.x & 63;
    const int wpb = blockDim.x >> 6;
    const int wid = blockIdx.x * wpb + wv;
    const int total = NC * nstrips * nb;
    if (wid >= total) return;

    const int band = wid % nb;
    const int t1 = wid / nb;
    const int strip = t1 % nstrips;
    const int img = t1 / nstrips;
    const int n = img / 3;

    const int Ho = H - (FILT - 1);
    const int Wo = W - (FILT - 1);
    const int a = band * B;                 // even (B even)
    if (a >= Ho) return;
    const int out_hi = min(a + B, Ho);
    const int bEnd = out_hi + (FILT - 1);   // input rows [a, bEnd)

    const int base = strip * 64;
    const float* xp = x + (size_t)img * H * W;
    const float* yp = y + (size_t)img * H * W;
    const int c0 = min(base + lane, W - 1);
    const int c1 = min(base + 64 + min(lane, 9), W - 1);  // halo: 1 cacheline
    const bool colv = (base + lane) < Wo;

    const float mv = dec_f(mm[0]) - dec_f(mm[1]);
    const float c1c = (0.01f * mv) * (0.01f * mv);
    const float c2c = (0.03f * mv) * (0.03f * mv);

    const int Wp = W >> 1;
    const size_t pbase = (size_t)img * (H >> 1) * Wp;

    v2f* bufE = &ring[wv][0][0];   // even rows
    v2f* bufO = &ring[wv][1][0];   // odd rows

    v2f acc01[FILT], acc23[FILT];
    float acc4[FILT];
#pragma unroll
    for (int s = 0; s < FILT; s++) {
        acc01[s] = (v2f){0.f, 0.f};
        acc23[s] = (v2f){0.f, 0.f};
        acc4[s] = 0.f;
    }

    float lcs = 0.f, lss = 0.f;

    // ---- prologue: prefetch rows a, a+1 into registers ----
    float ex0, ey0, ex1, ey1, ox0, oy0, ox1, oy1;
    {
        const float* xe = xp + (size_t)a * W;
        const float* ye = yp + (size_t)a * W;
        ex0 = xe[c0]; ey0 = ye[c0]; ex1 = xe[c1]; ey1 = ye[c1];
        ox0 = xe[W + c0]; oy0 = ye[W + c0];
        ox1 = xe[W + c1]; oy1 = ye[W + c1];
    }

#pragma unroll 1
    for (int r0 = a; r0 < bEnd; r0 += 22) {
#pragma unroll
        for (int p = 0; p < FILT; p++) {     // 11 double-steps, NO break
            const int r = r0 + 2 * p;
            if (r < bEnd) {
                const bool hasO = (r + 1 < bEnd);
                const int pe = (2 * p) % FILT;
                const int po = (2 * p + 1) % FILT;

                bufE[lane] = (v2f){ex0, ey0};
                if (lane < 10) bufE[64 + lane] = (v2f){ex1, ey1};
                if (hasO) {
                    bufO[lane] = (v2f){ox0, oy0};
                    if (lane < 10) bufO[64 + lane] = (v2f){ox1, oy1};
                }

                {
                    const int re = min(r + 2, bEnd - 1);
                    const int ro = min(r + 3, bEnd - 1);
                    const float* xe = xp + (size_t)re * W;
                    const float* ye = yp + (size_t)re * W;
                    const float* xo = xp + (size_t)ro * W;
                    const float* yo = yp + (size_t)ro * W;
                    ex0 = xe[c0]; ey0 = ye[c0]; ex1 = xe[c1]; ey1 = ye[c1];
                    ox0 = xo[c0]; oy0 = yo[c0]; ox1 = xo[c1]; oy1 = yo[c1];
                }

                if (do_pool && hasO && lane < 32) {
                    const int pc = (base >> 1) + lane;
                    if (pc < Wp) {
                        float4 qe = *(const float4*)&bufE[2 * lane];
                        float4 qo = *(const float4*)&bufO[2 * lane];
                        size_t o = pbase + (size_t)(r >> 1) * Wp + pc;
                        poolx[o] = 0.25f * (qe.x + qe.z + qo.x + qo.z);
                        pooly[o] = 0.25f * (qe.y + qe.w + qo.y + qo.w);
                    }
                }

                v2f h01e = (v2f){0.f, 0.f}, h23e = (v2f){0.f, 0.f};
                float h4e = 0.f;
#pragma unroll
                for (int k = 0; k < FILT; k++) {
                    v2f v = bufE[lane + k];
                    float w = gw.w[k];
                    v2f w2 = {w, w};
                    h01e = __builtin_elementwise_fma(w2, v, h01e);
                    v2f sq = v * v;
                    h23e = __builtin_elementwise_fma(w2, sq, h23e);
                    h4e = __builtin_fmaf(w, v.x * v.y, h4e);
                }
#pragma unroll
                for (int k = 0; k < FILT; k++) {
                    const int s = (pe - k + FILT) % FILT;
                    float w = gw.w[k];
                    v2f w2 = {w, w};
                    acc01[s] = __builtin_elementwise_fma(w2, h01e, acc01[s]);
                    acc23[s] = __builtin_elementwise_fma(w2, h23e, acc23[s]);
                    acc4[s] = __builtin_fmaf(w, h4e, acc4[s]);
                }
                const int eE = (pe + 1) % FILT;
                if (r >= a + (FILT - 1) && colv) {
                    float m1 = acc01[eE].x, m2 = acc01[eE].y;
                    float mu11 = m1 * m1, mu22 = m2 * m2, mu12 = m1 * m2;
                    float s1 = acc23[eE].x - mu11;
                    float s2 = acc23[eE].y - mu22;
                    float s12 = acc4[eE] - mu12;
                    float A = 2.f * s12 + c2c, Bv = s1 + s2 + c2c;
                    float Cv = 2.f * mu12 + c1c, Dv = mu11 + mu22 + c1c;
                    float r_ = __builtin_amdgcn_rcpf(Bv * Dv);
                    lcs += A * Dv * r_;
                    lss += Cv * A * r_;
                }
                acc01[eE] = (v2f){0.f, 0.f};
                acc23[eE] = (v2f){0.f, 0.f};
                acc4[eE] = 0.f;

                if (hasO) {
                    v2f h01o = (v2f){0.f, 0.f}, h23o = (v2f){0.f, 0.f};
                    float h4o = 0.f;
#pragma unroll
                    for (int k = 0; k < FILT; k++) {
                        v2f v = bufO[lane + k];
                        float w = gw.w[k];
                        v2f w2 = {w, w};
                        h01o = __builtin_elementwise_fma(w2, v, h01o);
                        v2f sq = v * v;
                        h23o = __builtin_elementwise_fma(w2, sq, h23o);
                        h4o = __builtin_fmaf(w, v.x * v.y, h4o);
                    }
#pragma unroll
                    for (int k = 0; k < FILT; k++) {
                        const int s = (po - k + FILT) % FILT;
                        float w = gw.w[k];
                        v2f w2 = {w, w};
                        acc01[s] = __builtin_elementwise_fma(w2, h01o, acc01[s]);
                        acc23[s] = __builtin_elementwise_fma(w2, h23o, acc23[s]);
                        acc4[s] = __builtin_fmaf(w, h4o, acc4[s]);
                    }
                    const int eO = (po + 1) % FILT;
                    if (r >= a + (FILT - 1) && colv) {
                        float m1 = acc01[eO].x, m2 = acc01[eO].y;
                        float mu11 = m1 * m1, mu22 = m2 * m2, mu12 = m1 * m2;
                        float s1 = acc23[eO].x - mu11;
                        float s2 = acc23[eO].y - mu22;
                        float s12 = acc4[eO] - mu12;
                        float A = 2.f * s12 + c2c, Bv = s1 + s2 + c2c;
                        float Cv = 2.f * mu12 + c1c, Dv = mu11 + mu22 + c1c;
                        float r_ = __builtin_amdgcn_rcpf(Bv * Dv);
                        lcs += A * Dv * r_;
                        lss += Cv * A * r_;
                    }
                    acc01[eO] = (v2f){0.f, 0.f};
                    acc23[eO] = (v2f){0.f, 0.f};
                    acc4[eO] = 0.f;
                }
            }
        }
    }

    for (int off = 32; off; off >>= 1) {
        lcs += __shfl_down(lcs, off);
        lss += __shfl_down(lss, off);
    }
    if (lane == 0) {
        atomicAdd(&cs_sum[n], lcs);
        atomicAdd(&ssim_sum[n], lss);
    }
}

// SSIM streaming over an LDS-resident tile (taps read directly; no staging).
__device__ __forceinline__ void ssim_lds_strip(
    const v2f* tile, int Wt, int Wo, int a, int out_hi, int lane,
    float c1c, float c2c, const GW& gw, float& lcs, float& lss)
{
    const int bEnd = out_hi + (FILT - 1);
    const int tl = min(lane, Wo - 1);       // taps tl..tl+10 stay inside row
    const bool colv = lane < Wo;

    v2f acc01[FILT], acc23[FILT];
    float acc4[FILT];
#pragma unroll
    for (int s = 0; s < FILT; s++) {
        acc01[s] = (v2f){0.f, 0.f};
        acc23[s] = (v2f){0.f, 0.f};
        acc4[s] = 0.f;
    }

#pragma unroll 1
    for (int r0 = a; r0 < bEnd; r0 += FILT) {
#pragma unroll
        for (int p = 0; p < FILT; p++) {
            const int r = r0 + p;
            if (r < bEnd) {
                const v2f* row = tile + (size_t)r * Wt;
                v2f h01 = (v2f){0.f, 0.f}, h23 = (v2f){0.f, 0.f};
                float h4 = 0.f;
#pragma unroll
                for (int k = 0; k < FILT; k++) {
                    v2f v = row[tl + k];
                    float w = gw.w[k];
                    v2f w2 = {w, w};
                    h01 = __builtin_elementwise_fma(w2, v, h01);
                    v2f sq = v * v;
                    h23 = __builtin_elementwise_fma(w2, sq, h23);
                    h4 = __builtin_fmaf(w, v.x * v.y, h4);
                }
#pragma unroll
                for (int k = 0; k < FILT; k++) {
                    const int s = (p - k + FILT) % FILT;
                    float w = gw.w[k];
                    v2f w2 = {w, w};
                    acc01[s] = __builtin_elementwise_fma(w2, h01, acc01[s]);
                    acc23[s] = __builtin_elementwise_fma(w2, h23, acc23[s]);
                    acc4[s] = __builtin_fmaf(w, h4, acc4[s]);
                }
                const int e = (p + 1) % FILT;
                if (r >= a + (FILT - 1) && colv) {
                    float m1 = acc01[e].x, m2 = acc01[e].y;
                    float mu11 = m1 * m1, mu22 = m2 * m2, mu12 = m1 * m2;
                    float s1 = acc23[e].x - mu11;
                    float s2 = acc23[e].y - mu22;
                    float s12 = acc4[e] - mu12;
                    float A = 2.f * s12 + c2c, Bv = s1 + s2 + c2c;
                    float Cv = 2.f * mu12 + c1c, Dv = mu11 + mu22 + c1c;
                    float r_ = __builtin_amdgcn_rcpf(Bv * Dv);
                    lcs += A * Dv * r_;
                    lss += Cv * A * r_;
                }
                acc01[e] = (v2f){0.f, 0.f};
                acc23[e] = (v2f){0.f, 0.f};
                acc4[e] = 0.f;
            }
        }
    }
}

// Fused levels 2-4: one block per (n,c) image. L2 streams from global
// (ring-staged) and pools into LDS; L3/L4 tap LDS tiles directly.
__global__ __launch_bounds__(1024) void ssim_tail(
    const float* __restrict__ x2, const float* __restrict__ y2,
    const unsigned* __restrict__ mm, float* __restrict__ ws2, GW gw)
{
    __shared__ v2f ring[16][2][80];
    __shared__ v2f buf3[64 * 64];
    __shared__ v2f buf4[32 * 32];

    const int img = blockIdx.x;        // 0..95
    const int n = img / 3;
    const int wv = threadIdx.x >> 6;
    const int lane = threadIdx.x & 63;

    float* cs2 = ws2 + 2 + 2 * 32;
    float* cs3 = ws2 + 2 + 3 * 32;
    float* cs4 = ws2 + 2 + 4 * 32;
    float* ss2 = ws2 + 2 + 5 * 32 + 2 * 32;
    float* ss3 = ws2 + 2 + 5 * 32 + 3 * 32;
    float* ss4 = ws2 + 2 + 5 * 32 + 4 * 32;

    const float mv = dec_f(mm[0]) - dec_f(mm[1]);
    const float c1c = (0.01f * mv) * (0.01f * mv);
    const float c2c = (0.03f * mv) * (0.03f * mv);

    // ---------------- L2: stream from global, pool -> buf3 ----------------
    {
        const int strip = wv >> 3;          // 0..1
        const int band = wv & 7;            // 0..7
        const int H = 128, W = 128, Ho = 118, B = 16;
        const int a = band * B;
        const int out_hi = min(a + B, Ho);
        const int bEnd = out_hi + (FILT - 1);
        const int base = strip * 64;
        const float* xp = x2 + (size_t)img * H * W;
        const float* yp = y2 + (size_t)img * H * W;
        const int c0 = min(base + lane, W - 1);
        const int c1 = min(base + 64 + min(lane, 9), W - 1);
        const bool colv = (base + lane) < Ho;   // Wo == Ho == 118

        v2f* bufA = &ring[wv][0][0];
        v2f* bufB = &ring[wv][1][0];

        v2f acc01[FILT], acc23[FILT];
        float acc4[FILT];
#pragma unroll
        for (int s = 0; s < FILT; s++) {
            acc01[s] = (v2f){0.f, 0.f};
            acc23[s] = (v2f){0.f, 0.f};
            acc4[s] = 0.f;
        }
        float lcs = 0.f, lss = 0.f;

        const float* xr = xp + (size_t)a * W;
        const float* yr = yp + (size_t)a * W;
        float pfx0 = xr[c0], pfy0 = yr[c0];
        float pfx1 = xr[c1], pfy1 = yr[c1];

#pragma unroll 1
        for (int r0 = a; r0 < bEnd; r0 += FILT) {
#pragma unroll
            for (int p = 0; p < FILT; p++) {
                const int r = r0 + p;
                if (r < bEnd) {
                    v2f* bufc = (r & 1) ? bufB : bufA;
                    v2f* bufo = (r & 1) ? bufA : bufB;

                    bufc[lane] = (v2f){pfx0, pfy0};
                    if (lane < 10) bufc[64 + lane] = (v2f){pfx1, pfy1};

                    {
                        const int rn = min(r + 1, bEnd - 1);
                        const float* xn = xp + (size_t)rn * W;
                        const float* yn = yp + (size_t)rn * W;
                        pfx0 = xn[c0]; pfy0 = yn[c0];
                        pfx1 = xn[c1]; pfy1 = yn[c1];
                    }

                    v2f h01 = (v2f){0.f, 0.f}, h23 = (v2f){0.f, 0.f};
                    float h4 = 0.f;
#pragma unroll
                    for (int k = 0; k < FILT; k++) {
                        v2f v = bufc[lane + k];
                        float w = gw.w[k];
                        v2f w2 = {w, w};
                        h01 = __builtin_elementwise_fma(w2, v, h01);
                        v2f sq = v * v;
                        h23 = __builtin_elementwise_fma(w2, sq, h23);
                        h4 = __builtin_fmaf(w, v.x * v.y, h4);
                    }
#pragma unroll
                    for (int k = 0; k < FILT; k++) {
                        const int s = (p - k + FILT) % FILT;
                        float w = gw.w[k];
                        v2f w2 = {w, w};
                        acc01[s] = __builtin_elementwise_fma(w2, h01, acc01[s]);
                        acc23[s] = __builtin_elementwise_fma(w2, h23, acc23[s]);
                        acc4[s] = __builtin_fmaf(w, h4, acc4[s]);
                    }
                    const int e = (p + 1) % FILT;
                    if (r >= a + (FILT - 1) && colv) {
                        float m1 = acc01[e].x, m2 = acc01[e].y;
                        float mu11 = m1 * m1, mu22 = m2 * m2, mu12 = m1 * m2;
                        float s1 = acc23[e].x - mu11;
                        float s2 = acc23[e].y - mu22;
                        float s12 = acc4[e] - mu12;
                        float A = 2.f * s12 + c2c, Bv = s1 + s2 + c2c;
                        float Cv = 2.f * mu12 + c1c, Dv = mu11 + mu22 + c1c;
                        float r_ = __builtin_amdgcn_rcpf(Bv * Dv);
                        lcs += A * Dv * r_;
                        lss += Cv * A * r_;
                    }
                    acc01[e] = (v2f){0.f, 0.f};
                    acc23[e] = (v2f){0.f, 0.f};
                    acc4[e] = 0.f;

                    // pool rows (r-1, r) -> buf3 (idempotent dup writes ok)
                    if ((r & 1) && r > a && lane < 32) {
                        const int pc = (base >> 1) + lane;   // 0..63
                        const int pr = r >> 1;               // 0..63
                        v2f q00 = bufo[2 * lane];
                        v2f q01 = bufo[2 * lane + 1];
                        v2f q10 = bufc[2 * lane];
                        v2f q11 = bufc[2 * lane + 1];
                        buf3[pr * 64 + pc] =
                            (q00 + q01 + q10 + q11) * (v2f){0.25f, 0.25f};
                    }
                }
            }
        }

        for (int off = 32; off; off >>= 1) {
            lcs += __shfl_down(lcs, off);
            lss += __shfl_down(lss, off);
        }
        if (lane == 0) {
            atomicAdd(&cs2[n], lcs);
            atomicAdd(&ss2[n], lss);
        }
    }
    __syncthreads();

    // ---------------- pool buf3 -> buf4 (one elem per thread) -------------
    {
        const int pr = threadIdx.x >> 5;    // 0..31
        const int pc = threadIdx.x & 31;    // 0..31
        v2f q = (buf3[(2 * pr) * 64 + 2 * pc] + buf3[(2 * pr) * 64 + 2 * pc + 1] +
                 buf3[(2 * pr + 1) * 64 + 2 * pc] + buf3[(2 * pr + 1) * 64 + 2 * pc + 1]) *
                (v2f){0.25f, 0.25f};
        buf4[pr * 32 + pc] = q;
    }
    __syncthreads();

    // ---------------- L3 (waves 0-13) / L4 (waves 14-15) ------------------
    {
        float lcs = 0.f, lss = 0.f;
        bool isL3 = (wv < 14);
        if (isL3) {
            const int a = wv * 4;
            ssim_lds_strip(buf3, 64, 54, a, min(a + 4, 54), lane,
                           c1c, c2c, gw, lcs, lss);
        } else {
            const int a = (wv - 14) * 12;
            ssim_lds_strip(buf4, 32, 22, a, min(a + 12, 22), lane,
                           c1c, c2c, gw, lcs, lss);
        }
        for (int off = 32; off; off >>= 1) {
            lcs += __shfl_down(lcs, off);
            lss += __shfl_down(lss, off);
        }
        if (lane == 0) {
            atomicAdd(isL3 ? &cs3[n] : &cs4[n], lcs);
            atomicAdd(isL3 ? &ss3[n] : &ss4[n], lss);
        }
    }
}

__global__ void final_kernel(const float* __restrict__ cs_sum,
                             const float* __restrict__ ssim_sum,
                             float* __restrict__ out)
{
    const float cnt[5] = {3.f * 502 * 502, 3.f * 246 * 246, 3.f * 118 * 118,
                          3.f * 54 * 54, 3.f * 22 * 22};
    const float wts[5] = {0.0448f, 0.2856f, 0.3001f, 0.2363f, 0.1333f};
    int n = threadIdx.x;
    float ms = 0.f;
    if (n < 32) {
        float ssim = ssim_sum[4 * 32 + n] / cnt[4];
        float t = powf(ssim, wts[4]);
        ms = 1.f;
        for (int l = 0; l < 4; l++) {
            float cs = cs_sum[l * 32 + n] / cnt[l];
            ms *= powf(cs, wts[l]) * t;  // faithful: ssim^w4 inside the product
        }
    }
    for (int off = 32; off; off >>= 1) ms += __shfl_down(ms, off);
    if (threadIdx.x == 0) out[0] = ms / 32.f;
}

extern "C" void kernel_launch(void* const* d_in, const int* in_sizes, int n_in,
                              void* d_out, int out_size, void* d_ws, size_t ws_size,
                              hipStream_t stream) {
    const float* x0 = (const float*)d_in[0];
    const float* y0 = (const float*)d_in[1];
    float* out = (float*)d_out;
    float* ws = (float*)d_ws;
    unsigned* mm = (unsigned*)d_ws;
    float* cs_sum = ws + 2;
    float* ssim_sum = ws + 2 + 5 * 32;

    const int N = 32, C = 3, NC = N * C;

    // pyramid buffers: only levels 1 and 2 are materialized now
    float* wp = ws + 512;
    float* pxw1 = wp; wp += (size_t)NC * 256 * 256;
    float* pyw1 = wp; wp += (size_t)NC * 256 * 256;
    float* pxw2 = wp; wp += (size_t)NC * 128 * 128;
    float* pyw2 = wp; wp += (size_t)NC * 128 * 128;

    // gaussian weights (softmax of -c^2/(2*sigma^2))
    GW gw;
    {
        double tmp[FILT], s = 0.0;
        for (int k = 0; k < FILT; k++) {
            double c = (double)k - (FILT - 1) / 2.0;
            tmp[k] = exp(-c * c / (2.0 * 1.5 * 1.5));
            s += tmp[k];
        }
        for (int k = 0; k < FILT; k++) gw.w[k] = (float)(tmp[k] / s);
    }

    init_acc<<<1, 256, 0, stream>>>(mm);
    long n4 = (long)NC * 512 * 512 / 4;
    minmax_kernel<<<2048, 256, 0, stream>>>((const float4*)y0, n4, mm);

    // L0: 1024-thread blocks (16 waves) -- block-residency experiment
    {
        int H = 512, Ho = 502, nstrips = 8, B = 64;
        int nb = (Ho + B - 1) / B;                  // 8
        int total = NC * nstrips * nb;              // 6144
        int grid = (total + 15) / 16;               // 384
        ssim_stream<<<grid, 1024, 0, stream>>>(
            x0, y0, H, H, NC, nstrips, nb, B, mm,
            cs_sum + 0 * 32, ssim_sum + 0 * 32, gw, pxw1, pyw1, 1);
    }
    // L1: 256-thread blocks (control, R10 geometry)
    {
        int H = 256, Ho = 246, nstrips = 4, B = 42;
        int nb = (Ho + B - 1) / B;                  // 6
        int total = NC * nstrips * nb;              // 2304
        int grid = (total + 3) / 4;                 // 576
        ssim_stream<<<grid, 256, 0, stream>>>(
            pxw1, pyw1, H, H, NC, nstrips, nb, B, mm,
            cs_sum + 1 * 32, ssim_sum + 1 * 32, gw, pxw2, pyw2, 1);
    }
    // L2+L3+L4 fused
    ssim_tail<<<NC, 1024, 0, stream>>>(pxw2, pyw2, mm, ws, gw);

    final_kernel<<<1, 64, 0, stream>>>(cs_sum, ssim_sum, out);
}

// Round 12
// 322.029 us; speedup vs baseline: 1.1826x; 1.1826x over previous
//
#include <hip/hip_runtime.h>
#include <cmath>

#define FILT 11

typedef float v2f __attribute__((ext_vector_type(2)));

struct GW { float w[FILT]; };

// ---- order-preserving float<->uint encode for atomic min/max ----
__device__ __forceinline__ unsigned enc_f(float f) {
    unsigned u = __float_as_uint(f);
    return (u & 0x80000000u) ? ~u : (u | 0x80000000u);
}
__device__ __forceinline__ float dec_f(unsigned u) {
    return (u & 0x80000000u) ? __uint_as_float(u & 0x7FFFFFFFu)
                             : __uint_as_float(~u);
}

__global__ void init_acc(unsigned* ws) {
    int t = threadIdx.x;
    if (t == 0) { ws[0] = 0u; ws[1] = 0xFFFFFFFFu; }
    for (int i = 2 + t; i < 512; i += blockDim.x) ws[i] = 0u;  // zero accs + ctr
}

__global__ void minmax_kernel(const float4* __restrict__ t, long n4, unsigned* mm) {
    unsigned mx = 0u, mn = 0xFFFFFFFFu;
    long stride = (long)gridDim.x * blockDim.x;
    for (long i = (long)blockIdx.x * blockDim.x + threadIdx.x; i < n4; i += stride) {
        float4 v = t[i];
        unsigned a = enc_f(v.x), b = enc_f(v.y), c = enc_f(v.z), d = enc_f(v.w);
        mx = max(mx, max(max(a, b), max(c, d)));
        mn = min(mn, min(min(a, b), min(c, d)));
    }
    for (int off = 32; off; off >>= 1) {
        mx = max(mx, (unsigned)__shfl_down((int)mx, off));
        mn = min(mn, (unsigned)__shfl_down((int)mn, off));
    }
    __shared__ unsigned smx[4], smn[4];
    int wid = threadIdx.x >> 6, lane = threadIdx.x & 63;
    if (lane == 0) { smx[wid] = mx; smn[wid] = mn; }
    __syncthreads();
    if (threadIdx.x == 0) {
        for (int i = 1; i < 4; i++) { mx = max(mx, smx[i]); mn = min(mn, smn[i]); }
        atomicMax(&mm[0], mx);
        atomicMin(&mm[1], mn);
    }
}

// Row-streaming fused SSIM + pool, DOUBLE-ROW steps (R10 core) with
// instruction diet: frozen-clamp incremented prefetch pointers and
// uniform incremental pool row offset (no per-step re-derivation).
__global__ __launch_bounds__(256) void ssim_stream(
    const float* __restrict__ x, const float* __restrict__ y,
    int H, int W, int NC, int nstrips, int nb, int B,
    const unsigned* __restrict__ mm,
    float* __restrict__ cs_sum, float* __restrict__ ssim_sum, GW gw,
    float* __restrict__ poolx, float* __restrict__ pooly, int do_pool)
{
    __shared__ v2f ring[4][2][80];

    const int wv = threadIdx.x >> 6;
    const int lane = threadIdx.x & 63;
    const int wid = blockIdx.x * 4 + wv;
    const int total = NC * nstrips * nb;
    if (wid >= total) return;

    const int band = wid % nb;
    const int t1 = wid / nb;
    const int strip = t1 % nstrips;
    const int img = t1 / nstrips;
    const int n = img / 3;

    const int Ho = H - (FILT - 1);
    const int Wo = W - (FILT - 1);
    const int a = band * B;                 // even (B even)
    if (a >= Ho) return;
    const int out_hi = min(a + B, Ho);
    const int bEnd = out_hi + (FILT - 1);   // input rows [a, bEnd)

    const int base = strip * 64;
    const float* xp = x + (size_t)img * H * W;
    const float* yp = y + (size_t)img * H * W;
    const int c0 = min(base + lane, W - 1);
    const int c1 = min(base + 64 + min(lane, 9), W - 1);  // halo: 1 cacheline
    const bool colv = (base + lane) < Wo;

    const float mv = dec_f(mm[0]) - dec_f(mm[1]);
    const float c1c = (0.01f * mv) * (0.01f * mv);
    const float c2c = (0.03f * mv) * (0.03f * mv);

    const int Wp = W >> 1;
    // uniform (wave-invariant) incremental pool row offset
    size_t orow = (size_t)img * (H >> 1) * Wp + (size_t)(a >> 1) * Wp;
    const int pc = (base >> 1) + lane;
    const bool poolv = (lane < 32) && (pc < Wp);

    v2f* bufE = &ring[wv][0][0];   // even rows
    v2f* bufO = &ring[wv][1][0];   // odd rows

    v2f acc01[FILT], acc23[FILT];
    float acc4[FILT];
#pragma unroll
    for (int s = 0; s < FILT; s++) {
        acc01[s] = (v2f){0.f, 0.f};
        acc23[s] = (v2f){0.f, 0.f};
        acc4[s] = 0.f;
    }

    float lcs = 0.f, lss = 0.f;

    // ---- prologue: rows a, a+1 into registers; pointers at rows a+2, a+3 ----
    float ex0, ey0, ex1, ey1, ox0, oy0, ox1, oy1;
    {
        const float* xe = xp + (size_t)a * W;
        const float* ye = yp + (size_t)a * W;
        ex0 = xe[c0]; ey0 = ye[c0]; ex1 = xe[c1]; ey1 = ye[c1];
        ox0 = xe[W + c0]; oy0 = ye[W + c0];
        ox1 = xe[W + c1]; oy1 = ye[W + c1];
    }
    const float* xe = xp + (size_t)(a + 2) * W;
    const float* ye = yp + (size_t)(a + 2) * W;
    const float* xo = xp + (size_t)(a + 3) * W;
    const float* yo = yp + (size_t)(a + 3) * W;

#pragma unroll 1
    for (int r0 = a; r0 < bEnd; r0 += 22) {
#pragma unroll
        for (int p = 0; p < FILT; p++) {     // 11 double-steps, NO break
            const int r = r0 + 2 * p;
            if (r < bEnd) {
                const bool hasO = (r + 1 < bEnd);
                const int pe = (2 * p) % FILT;
                const int po = (2 * p + 1) % FILT;

                // ---- stage rows r, r+1 (same-wave DS in order) ----
                bufE[lane] = (v2f){ex0, ey0};
                if (lane < 10) bufE[64 + lane] = (v2f){ex1, ey1};
                if (hasO) {
                    bufO[lane] = (v2f){ox0, oy0};
                    if (lane < 10) bufO[64 + lane] = (v2f){ox1, oy1};
                }

                // ---- prefetch rows r+2, r+3 from frozen-clamp pointers ----
                ex0 = xe[c0]; ey0 = ye[c0]; ex1 = xe[c1]; ey1 = ye[c1];
                ox0 = xo[c0]; oy0 = yo[c0]; ox1 = xo[c1]; oy1 = yo[c1];
                {
                    const int adv = (r + 4 < bEnd) ? 2 * W : 0;
                    xe += adv; ye += adv; xo += adv; yo += adv;
                }

                // ---- fused 2x2 avg pool on pair (r, r+1) ----
                if (do_pool && hasO && poolv) {
                    float4 qe = *(const float4*)&bufE[2 * lane];
                    float4 qo = *(const float4*)&bufO[2 * lane];
                    poolx[orow + pc] = 0.25f * (qe.x + qe.z + qo.x + qo.z);
                    pooly[orow + pc] = 0.25f * (qe.y + qe.w + qo.y + qo.w);
                }
                orow += Wp;

                // ---- horizontal 11-tap blur row r ----
                v2f h01e = (v2f){0.f, 0.f}, h23e = (v2f){0.f, 0.f};
                float h4e = 0.f;
#pragma unroll
                for (int k = 0; k < FILT; k++) {
                    v2f v = bufE[lane + k];
                    float w = gw.w[k];
                    v2f w2 = {w, w};
                    h01e = __builtin_elementwise_fma(w2, v, h01e);
                    v2f sq = v * v;
                    h23e = __builtin_elementwise_fma(w2, sq, h23e);
                    h4e = __builtin_fmaf(w, v.x * v.y, h4e);
                }
#pragma unroll
                for (int k = 0; k < FILT; k++) {
                    const int s = (pe - k + FILT) % FILT;
                    float w = gw.w[k];
                    v2f w2 = {w, w};
                    acc01[s] = __builtin_elementwise_fma(w2, h01e, acc01[s]);
                    acc23[s] = __builtin_elementwise_fma(w2, h23e, acc23[s]);
                    acc4[s] = __builtin_fmaf(w, h4e, acc4[s]);
                }
                const int eE = (pe + 1) % FILT;
                if (r >= a + (FILT - 1) && colv) {
                    float m1 = acc01[eE].x, m2 = acc01[eE].y;
                    float mu11 = m1 * m1, mu22 = m2 * m2, mu12 = m1 * m2;
                    float s1 = acc23[eE].x - mu11;
                    float s2 = acc23[eE].y - mu22;
                    float s12 = acc4[eE] - mu12;
                    float A = 2.f * s12 + c2c, Bv = s1 + s2 + c2c;
                    float Cv = 2.f * mu12 + c1c, Dv = mu11 + mu22 + c1c;
                    float r_ = __builtin_amdgcn_rcpf(Bv * Dv);
                    lcs += A * Dv * r_;
                    lss += Cv * A * r_;
                }
                acc01[eE] = (v2f){0.f, 0.f};
                acc23[eE] = (v2f){0.f, 0.f};
                acc4[eE] = 0.f;

                // ---- row r+1 ----
                if (hasO) {
                    v2f h01o = (v2f){0.f, 0.f}, h23o = (v2f){0.f, 0.f};
                    float h4o = 0.f;
#pragma unroll
                    for (int k = 0; k < FILT; k++) {
                        v2f v = bufO[lane + k];
                        float w = gw.w[k];
                        v2f w2 = {w, w};
                        h01o = __builtin_elementwise_fma(w2, v, h01o);
                        v2f sq = v * v;
                        h23o = __builtin_elementwise_fma(w2, sq, h23o);
                        h4o = __builtin_fmaf(w, v.x * v.y, h4o);
                    }
#pragma unroll
                    for (int k = 0; k < FILT; k++) {
                        const int s = (po - k + FILT) % FILT;
                        float w = gw.w[k];
                        v2f w2 = {w, w};
                        acc01[s] = __builtin_elementwise_fma(w2, h01o, acc01[s]);
                        acc23[s] = __builtin_elementwise_fma(w2, h23o, acc23[s]);
                        acc4[s] = __builtin_fmaf(w, h4o, acc4[s]);
                    }
                    const int eO = (po + 1) % FILT;
                    if (r >= a + (FILT - 1) && colv) {
                        float m1 = acc01[eO].x, m2 = acc01[eO].y;
                        float mu11 = m1 * m1, mu22 = m2 * m2, mu12 = m1 * m2;
                        float s1 = acc23[eO].x - mu11;
                        float s2 = acc23[eO].y - mu22;
                        float s12 = acc4[eO] - mu12;
                        float A = 2.f * s12 + c2c, Bv = s1 + s2 + c2c;
                        float Cv = 2.f * mu12 + c1c, Dv = mu11 + mu22 + c1c;
                        float r_ = __builtin_amdgcn_rcpf(Bv * Dv);
                        lcs += A * Dv * r_;
                        lss += Cv * A * r_;
                    }
                    acc01[eO] = (v2f){0.f, 0.f};
                    acc23[eO] = (v2f){0.f, 0.f};
                    acc4[eO] = 0.f;
                }
            }
        }
    }

    for (int off = 32; off; off >>= 1) {
        lcs += __shfl_down(lcs, off);
        lss += __shfl_down(lss, off);
    }
    if (lane == 0) {
        atomicAdd(&cs_sum[n], lcs);
        atomicAdd(&ssim_sum[n], lss);
    }
}

// SSIM streaming over an LDS-resident tile (taps read directly; no staging).
__device__ __forceinline__ void ssim_lds_strip(
    const v2f* tile, int Wt, int Wo, int a, int out_hi, int lane,
    float c1c, float c2c, const GW& gw, float& lcs, float& lss)
{
    const int bEnd = out_hi + (FILT - 1);
    const int tl = min(lane, Wo - 1);
    const bool colv = lane < Wo;

    v2f acc01[FILT], acc23[FILT];
    float acc4[FILT];
#pragma unroll
    for (int s = 0; s < FILT; s++) {
        acc01[s] = (v2f){0.f, 0.f};
        acc23[s] = (v2f){0.f, 0.f};
        acc4[s] = 0.f;
    }

#pragma unroll 1
    for (int r0 = a; r0 < bEnd; r0 += FILT) {
#pragma unroll
        for (int p = 0; p < FILT; p++) {
            const int r = r0 + p;
            if (r < bEnd) {
                const v2f* row = tile + (size_t)r * Wt;
                v2f h01 = (v2f){0.f, 0.f}, h23 = (v2f){0.f, 0.f};
                float h4 = 0.f;
#pragma unroll
                for (int k = 0; k < FILT; k++) {
                    v2f v = row[tl + k];
                    float w = gw.w[k];
                    v2f w2 = {w, w};
                    h01 = __builtin_elementwise_fma(w2, v, h01);
                    v2f sq = v * v;
                    h23 = __builtin_elementwise_fma(w2, sq, h23);
                    h4 = __builtin_fmaf(w, v.x * v.y, h4);
                }
#pragma unroll
                for (int k = 0; k < FILT; k++) {
                    const int s = (p - k + FILT) % FILT;
                    float w = gw.w[k];
                    v2f w2 = {w, w};
                    acc01[s] = __builtin_elementwise_fma(w2, h01, acc01[s]);
                    acc23[s] = __builtin_elementwise_fma(w2, h23, acc23[s]);
                    acc4[s] = __builtin_fmaf(w, h4, acc4[s]);
                }
                const int e = (p + 1) % FILT;
                if (r >= a + (FILT - 1) && colv) {
                    float m1 = acc01[e].x, m2 = acc01[e].y;
                    float mu11 = m1 * m1, mu22 = m2 * m2, mu12 = m1 * m2;
                    float s1 = acc23[e].x - mu11;
                    float s2 = acc23[e].y - mu22;
                    float s12 = acc4[e] - mu12;
                    float A = 2.f * s12 + c2c, Bv = s1 + s2 + c2c;
                    float Cv = 2.f * mu12 + c1c, Dv = mu11 + mu22 + c1c;
                    float r_ = __builtin_amdgcn_rcpf(Bv * Dv);
                    lcs += A * Dv * r_;
                    lss += Cv * A * r_;
                }
                acc01[e] = (v2f){0.f, 0.f};
                acc23[e] = (v2f){0.f, 0.f};
                acc4[e] = 0.f;
            }
        }
    }
}

// Fused levels 2-4 + final reduction ("last block" pattern, no spin barrier).
__global__ __launch_bounds__(1024) void ssim_tail(
    const float* __restrict__ x2, const float* __restrict__ y2,
    const unsigned* __restrict__ mm, float* __restrict__ ws2, GW gw,
    float* __restrict__ outp)
{
    __shared__ v2f ring[16][2][80];
    __shared__ v2f buf3[64 * 64];
    __shared__ v2f buf4[32 * 32];
    __shared__ int isLast;

    const int img = blockIdx.x;        // 0..95
    const int n = img / 3;
    const int wv = threadIdx.x >> 6;
    const int lane = threadIdx.x & 63;

    float* cs2 = ws2 + 2 + 2 * 32;
    float* cs3 = ws2 + 2 + 3 * 32;
    float* cs4 = ws2 + 2 + 4 * 32;
    float* ss2 = ws2 + 2 + 5 * 32 + 2 * 32;
    float* ss3 = ws2 + 2 + 5 * 32 + 3 * 32;
    float* ss4 = ws2 + 2 + 5 * 32 + 4 * 32;

    const float mv = dec_f(mm[0]) - dec_f(mm[1]);
    const float c1c = (0.01f * mv) * (0.01f * mv);
    const float c2c = (0.03f * mv) * (0.03f * mv);

    // ---------------- L2: stream from global, pool -> buf3 ----------------
    {
        const int strip = wv >> 3;          // 0..1
        const int band = wv & 7;            // 0..7
        const int H = 128, W = 128, Ho = 118, B = 16;
        const int a = band * B;
        const int out_hi = min(a + B, Ho);
        const int bEnd = out_hi + (FILT - 1);
        const int base = strip * 64;
        const float* xp = x2 + (size_t)img * H * W;
        const float* yp = y2 + (size_t)img * H * W;
        const int c0 = min(base + lane, W - 1);
        const int c1 = min(base + 64 + min(lane, 9), W - 1);
        const bool colv = (base + lane) < Ho;

        v2f* bufA = &ring[wv][0][0];
        v2f* bufB = &ring[wv][1][0];

        v2f acc01[FILT], acc23[FILT];
        float acc4[FILT];
#pragma unroll
        for (int s = 0; s < FILT; s++) {
            acc01[s] = (v2f){0.f, 0.f};
            acc23[s] = (v2f){0.f, 0.f};
            acc4[s] = 0.f;
        }
        float lcs = 0.f, lss = 0.f;

        const float* xr = xp + (size_t)a * W;
        const float* yr = yp + (size_t)a * W;
        float pfx0 = xr[c0], pfy0 = yr[c0];
        float pfx1 = xr[c1], pfy1 = yr[c1];

#pragma unroll 1
        for (int r0 = a; r0 < bEnd; r0 += FILT) {
#pragma unroll
            for (int p = 0; p < FILT; p++) {
                const int r = r0 + p;
                if (r < bEnd) {
                    v2f* bufc = (r & 1) ? bufB : bufA;
                    v2f* bufo = (r & 1) ? bufA : bufB;

                    bufc[lane] = (v2f){pfx0, pfy0};
                    if (lane < 10) bufc[64 + lane] = (v2f){pfx1, pfy1};

                    {
                        const int rn = min(r + 1, bEnd - 1);
                        const float* xn = xp + (size_t)rn * W;
                        const float* yn = yp + (size_t)rn * W;
                        pfx0 = xn[c0]; pfy0 = yn[c0];
                        pfx1 = xn[c1]; pfy1 = yn[c1];
                    }

                    v2f h01 = (v2f){0.f, 0.f}, h23 = (v2f){0.f, 0.f};
                    float h4 = 0.f;
#pragma unroll
                    for (int k = 0; k < FILT; k++) {
                        v2f v = bufc[lane + k];
                        float w = gw.w[k];
                        v2f w2 = {w, w};
                        h01 = __builtin_elementwise_fma(w2, v, h01);
                        v2f sq = v * v;
                        h23 = __builtin_elementwise_fma(w2, sq, h23);
                        h4 = __builtin_fmaf(w, v.x * v.y, h4);
                    }
#pragma unroll
                    for (int k = 0; k < FILT; k++) {
                        const int s = (p - k + FILT) % FILT;
                        float w = gw.w[k];
                        v2f w2 = {w, w};
                        acc01[s] = __builtin_elementwise_fma(w2, h01, acc01[s]);
                        acc23[s] = __builtin_elementwise_fma(w2, h23, acc23[s]);
                        acc4[s] = __builtin_fmaf(w, h4, acc4[s]);
                    }
                    const int e = (p + 1) % FILT;
                    if (r >= a + (FILT - 1) && colv) {
                        float m1 = acc01[e].x, m2 = acc01[e].y;
                        float mu11 = m1 * m1, mu22 = m2 * m2, mu12 = m1 * m2;
                        float s1 = acc23[e].x - mu11;
                        float s2 = acc23[e].y - mu22;
                        float s12 = acc4[e] - mu12;
                        float A = 2.f * s12 + c2c, Bv = s1 + s2 + c2c;
                        float Cv = 2.f * mu12 + c1c, Dv = mu11 + mu22 + c1c;
                        float r_ = __builtin_amdgcn_rcpf(Bv * Dv);
                        lcs += A * Dv * r_;
                        lss += Cv * A * r_;
                    }
                    acc01[e] = (v2f){0.f, 0.f};
                    acc23[e] = (v2f){0.f, 0.f};
                    acc4[e] = 0.f;

                    if ((r & 1) && r > a && lane < 32) {
                        const int pc = (base >> 1) + lane;
                        const int pr = r >> 1;
                        v2f q00 = bufo[2 * lane];
                        v2f q01 = bufo[2 * lane + 1];
                        v2f q10 = bufc[2 * lane];
                        v2f q11 = bufc[2 * lane + 1];
                        buf3[pr * 64 + pc] =
                            (q00 + q01 + q10 + q11) * (v2f){0.25f, 0.25f};
                    }
                }
            }
        }

        for (int off = 32; off; off >>= 1) {
            lcs += __shfl_down(lcs, off);
            lss += __shfl_down(lss, off);
        }
        if (lane == 0) {
            atomicAdd(&cs2[n], lcs);
            atomicAdd(&ss2[n], lss);
        }
    }
    __syncthreads();

    // ---------------- pool buf3 -> buf4 ----------------
    {
        const int pr = threadIdx.x >> 5;
        const int pc = threadIdx.x & 31;
        v2f q = (buf3[(2 * pr) * 64 + 2 * pc] + buf3[(2 * pr) * 64 + 2 * pc + 1] +
                 buf3[(2 * pr + 1) * 64 + 2 * pc] + buf3[(2 * pr + 1) * 64 + 2 * pc + 1]) *
                (v2f){0.25f, 0.25f};
        buf4[pr * 32 + pc] = q;
    }
    __syncthreads();

    // ---------------- L3 (waves 0-13) / L4 (waves 14-15) ------------------
    {
        float lcs = 0.f, lss = 0.f;
        bool isL3 = (wv < 14);
        if (isL3) {
            const int a = wv * 4;
            ssim_lds_strip(buf3, 64, 54, a, min(a + 4, 54), lane,
                           c1c, c2c, gw, lcs, lss);
        } else {
            const int a = (wv - 14) * 12;
            ssim_lds_strip(buf4, 32, 22, a, min(a + 12, 22), lane,
                           c1c, c2c, gw, lcs, lss);
        }
        for (int off = 32; off; off >>= 1) {
            lcs += __shfl_down(lcs, off);
            lss += __shfl_down(lss, off);
        }
        if (lane == 0) {
            atomicAdd(isL3 ? &cs3[n] : &cs4[n], lcs);
            atomicAdd(isL3 ? &ss3[n] : &ss4[n], lss);
        }
    }

    // ---------------- last-block final reduction ----------------
    __syncthreads();
    __threadfence();
    if (threadIdx.x == 0) {
        int old = atomicAdd((int*)(ws2 + 500), 1);
        isLast = (old == (int)gridDim.x - 1);
    }
    __syncthreads();
    if (isLast && threadIdx.x < 64) {
        const float cnt[5] = {3.f * 502 * 502, 3.f * 246 * 246, 3.f * 118 * 118,
                              3.f * 54 * 54, 3.f * 22 * 22};
        const float wts[5] = {0.0448f, 0.2856f, 0.3001f, 0.2363f, 0.1333f};
        int nn = threadIdx.x;
        float ms = 0.f;
        if (nn < 32) {
            float* cs = ws2 + 2;
            float* ss = ws2 + 2 + 5 * 32;
            float ssim = atomicAdd(&ss[4 * 32 + nn], 0.f) / cnt[4];
            float t = powf(ssim, wts[4]);
            ms = 1.f;
            for (int l = 0; l < 4; l++) {
                float cv = atomicAdd(&cs[l * 32 + nn], 0.f) / cnt[l];
                ms *= powf(cv, wts[l]) * t;  // faithful: ssim^w4 inside product
            }
        }
        for (int off = 32; off; off >>= 1) ms += __shfl_down(ms, off);
        if (threadIdx.x == 0) outp[0] = ms / 32.f;
    }
}

extern "C" void kernel_launch(void* const* d_in, const int* in_sizes, int n_in,
                              void* d_out, int out_size, void* d_ws, size_t ws_size,
                              hipStream_t stream) {
    const float* x0 = (const float*)d_in[0];
    const float* y0 = (const float*)d_in[1];
    float* out = (float*)d_out;
    float* ws = (float*)d_ws;
    unsigned* mm = (unsigned*)d_ws;
    float* cs_sum = ws + 2;
    float* ssim_sum = ws + 2 + 5 * 32;

    const int N = 32, C = 3, NC = N * C;

    // pyramid buffers: only levels 1 and 2 materialized
    float* wp = ws + 512;
    float* pxw1 = wp; wp += (size_t)NC * 256 * 256;
    float* pyw1 = wp; wp += (size_t)NC * 256 * 256;
    float* pxw2 = wp; wp += (size_t)NC * 128 * 128;
    float* pyw2 = wp; wp += (size_t)NC * 128 * 128;

    // gaussian weights (softmax of -c^2/(2*sigma^2))
    GW gw;
    {
        double tmp[FILT], s = 0.0;
        for (int k = 0; k < FILT; k++) {
            double c = (double)k - (FILT - 1) / 2.0;
            tmp[k] = exp(-c * c / (2.0 * 1.5 * 1.5));
            s += tmp[k];
        }
        for (int k = 0; k < FILT; k++) gw.w[k] = (float)(tmp[k] / s);
    }

    init_acc<<<1, 256, 0, stream>>>(mm);
    long n4 = (long)NC * 512 * 512 / 4;
    minmax_kernel<<<2048, 256, 0, stream>>>((const float4*)y0, n4, mm);

    // L0: R10 geometry (256-thr blocks), dieted core
    {
        int H = 512, Ho = 502, nstrips = 8, B = 64;
        int nb = (Ho + B - 1) / B;                  // 8
        int total = NC * nstrips * nb;              // 6144
        int grid = (total + 3) / 4;                 // 1536
        ssim_stream<<<grid, 256, 0, stream>>>(
            x0, y0, H, H, NC, nstrips, nb, B, mm,
            cs_sum + 0 * 32, ssim_sum + 0 * 32, gw, pxw1, pyw1, 1);
    }
    // L1: finer bands (B=32) for wave count
    {
        int H = 256, Ho = 246, nstrips = 4, B = 32;
        int nb = (Ho + B - 1) / B;                  // 8
        int total = NC * nstrips * nb;              // 3072
        int grid = (total + 3) / 4;                 // 768
        ssim_stream<<<grid, 256, 0, stream>>>(
            pxw1, pyw1, H, H, NC, nstrips, nb, B, mm,
            cs_sum + 1 * 32, ssim_sum + 1 * 32, gw, pxw2, pyw2, 1);
    }
    // L2+L3+L4 + final fused
    ssim_tail<<<NC, 1024, 0, stream>>>(pxw2, pyw2, mm, ws, gw, out);
}

// Round 13
// 291.077 us; speedup vs baseline: 1.3084x; 1.1063x over previous
//
#include <hip/hip_runtime.h>
#include <cmath>

#define FILT 11

typedef float v2f __attribute__((ext_vector_type(2)));

struct GW { float w[FILT]; };

// ---- order-preserving float<->uint encode for atomic min/max ----
__device__ __forceinline__ unsigned enc_f(float f) {
    unsigned u = __float_as_uint(f);
    return (u & 0x80000000u) ? ~u : (u | 0x80000000u);
}
__device__ __forceinline__ float dec_f(unsigned u) {
    return (u & 0x80000000u) ? __uint_as_float(u & 0x7FFFFFFFu)
                             : __uint_as_float(~u);
}

__global__ void init_acc(unsigned* ws) {
    int t = threadIdx.x;
    if (t == 0) { ws[0] = 0u; ws[1] = 0xFFFFFFFFu; }
    for (int i = 2 + t; i < 512; i += blockDim.x) ws[i] = 0u;  // zero accs + ctr
}

__global__ void minmax_kernel(const float4* __restrict__ t, long n4, unsigned* mm) {
    unsigned mx = 0u, mn = 0xFFFFFFFFu;
    long stride = (long)gridDim.x * blockDim.x;
    for (long i = (long)blockIdx.x * blockDim.x + threadIdx.x; i < n4; i += stride) {
        float4 v = t[i];
        unsigned a = enc_f(v.x), b = enc_f(v.y), c = enc_f(v.z), d = enc_f(v.w);
        mx = max(mx, max(max(a, b), max(c, d)));
        mn = min(mn, min(min(a, b), min(c, d)));
    }
    for (int off = 32; off; off >>= 1) {
        mx = max(mx, (unsigned)__shfl_down((int)mx, off));
        mn = min(mn, (unsigned)__shfl_down((int)mn, off));
    }
    __shared__ unsigned smx[4], smn[4];
    int wid = threadIdx.x >> 6, lane = threadIdx.x & 63;
    if (lane == 0) { smx[wid] = mx; smn[wid] = mn; }
    __syncthreads();
    if (threadIdx.x == 0) {
        for (int i = 1; i < 4; i++) { mx = max(mx, smx[i]); mn = min(mn, smn[i]); }
        atomicMax(&mm[0], mx);
        atomicMin(&mm[1], mn);
    }
}

// Row-streaming fused SSIM + pool, 2 ADJACENT output cols per lane,
// 128-wide strips. Taps = 6 aligned ds_read_b128 per row (covers both cols);
// staging = 1 ds_write_b128 per row (+5-lane halo); pool straight from regs.
__global__ __launch_bounds__(256) void ssim_stream2(
    const float* __restrict__ x, const float* __restrict__ y,
    int H, int W, int NC, int nstrips, int nb, int B,
    const unsigned* __restrict__ mm,
    float* __restrict__ cs_sum, float* __restrict__ ssim_sum, GW gw,
    float* __restrict__ poolx, float* __restrict__ pooly, int do_pool)
{
    __shared__ v2f ring[4][2][144];   // 138 used/buf; 1152B stride (16B-aligned)

    const int wv = threadIdx.x >> 6;
    const int lane = threadIdx.x & 63;
    const int wid = blockIdx.x * 4 + wv;
    const int total = NC * nstrips * nb;
    if (wid >= total) return;

    const int band = wid % nb;
    const int t1 = wid / nb;
    const int strip = t1 % nstrips;
    const int img = t1 / nstrips;
    const int n = img / 3;

    const int Ho = H - (FILT - 1);
    const int Wo = W - (FILT - 1);
    const int a = band * B;                 // even (B even)
    if (a >= Ho) return;
    const int out_hi = min(a + B, Ho);
    const int bEnd = out_hi + (FILT - 1);   // input rows [a, bEnd), even count

    const int base = strip * 128;
    const float* xp = x + (size_t)img * H * W;
    const float* yp = y + (size_t)img * H * W;
    const int cA = min(base + 2 * lane, W - 2);          // main float2 col
    const int cH = min(base + 128 + 2 * lane, W - 2);    // halo float2 col
    const bool colvA = (base + 2 * lane) < Wo;
    const bool colvB = (base + 2 * lane + 1) < Wo;

    const float mv = dec_f(mm[0]) - dec_f(mm[1]);
    const float c1c = (0.01f * mv) * (0.01f * mv);
    const float c2c = (0.03f * mv) * (0.03f * mv);

    const int Wp = W >> 1;
    size_t orow = (size_t)img * (H >> 1) * Wp + (size_t)(a >> 1) * Wp;
    const int pc = (base >> 1) + lane;
    const bool poolv = pc < Wp;

    v2f* bufE = &ring[wv][0][0];   // even rows
    v2f* bufO = &ring[wv][1][0];   // odd rows

    // two scalar accumulator ring sets (col A, col B)
    v2f aA01[FILT], aA23[FILT], aB01[FILT], aB23[FILT];
    float aA4[FILT], aB4[FILT];
#pragma unroll
    for (int s = 0; s < FILT; s++) {
        aA01[s] = (v2f){0.f, 0.f}; aA23[s] = (v2f){0.f, 0.f}; aA4[s] = 0.f;
        aB01[s] = (v2f){0.f, 0.f}; aB23[s] = (v2f){0.f, 0.f}; aB4[s] = 0.f;
    }

    float lcs = 0.f, lss = 0.f;

    // ---- prologue: rows a, a+1 into regs; pointers at rows a+2, a+3 ----
    float2 fxE, fyE, fxO, fyO, hxE, hyE, hxO, hyO;
    {
        const float* x0r = xp + (size_t)a * W;
        const float* y0r = yp + (size_t)a * W;
        fxE = *(const float2*)&x0r[cA]; fyE = *(const float2*)&y0r[cA];
        fxO = *(const float2*)&x0r[W + cA]; fyO = *(const float2*)&y0r[W + cA];
        if (lane < 5) {
            hxE = *(const float2*)&x0r[cH]; hyE = *(const float2*)&y0r[cH];
            hxO = *(const float2*)&x0r[W + cH]; hyO = *(const float2*)&y0r[W + cH];
        }
    }
    const float* xe = xp + (size_t)(a + 2) * W;
    const float* ye = yp + (size_t)(a + 2) * W;
    const float* xo = xp + (size_t)(a + 3) * W;
    const float* yo = yp + (size_t)(a + 3) * W;

#pragma unroll 1
    for (int r0 = a; r0 < bEnd; r0 += 22) {
#pragma unroll
        for (int p = 0; p < FILT; p++) {     // 11 double-steps, NO break
            const int r = r0 + 2 * p;
            if (r < bEnd) {
                const int pe = (2 * p) % FILT;
                const int po = (2 * p + 1) % FILT;

                // ---- 1. stage rows r, r+1 (b128 writes) ----
                *(float4*)&bufE[2 * lane] = make_float4(fxE.x, fyE.x, fxE.y, fyE.y);
                *(float4*)&bufO[2 * lane] = make_float4(fxO.x, fyO.x, fxO.y, fyO.y);
                if (lane < 5) {
                    *(float4*)&bufE[128 + 2 * lane] = make_float4(hxE.x, hyE.x, hxE.y, hyE.y);
                    *(float4*)&bufO[128 + 2 * lane] = make_float4(hxO.x, hyO.x, hxO.y, hyO.y);
                }

                // ---- 2. pool (r, r+1) straight from registers ----
                if (do_pool && poolv) {
                    poolx[orow + pc] = 0.25f * (fxE.x + fxE.y + fxO.x + fxO.y);
                    pooly[orow + pc] = 0.25f * (fyE.x + fyE.y + fyO.x + fyO.y);
                }
                orow += Wp;

                // ---- 3. prefetch rows r+2, r+3 ----
                fxE = *(const float2*)&xe[cA]; fyE = *(const float2*)&ye[cA];
                fxO = *(const float2*)&xo[cA]; fyO = *(const float2*)&yo[cA];
                if (lane < 5) {
                    hxE = *(const float2*)&xe[cH]; hyE = *(const float2*)&ye[cH];
                    hxO = *(const float2*)&xo[cH]; hyO = *(const float2*)&yo[cH];
                }
                {
                    const int adv = (r + 4 < bEnd) ? 2 * W : 0;
                    xe += adv; ye += adv; xo += adv; yo += adv;
                }

                // ======== row r (even, phase pe) ========
                {
                    float4 t0 = *(const float4*)&bufE[2 * lane + 0];
                    float4 t1 = *(const float4*)&bufE[2 * lane + 2];
                    float4 t2 = *(const float4*)&bufE[2 * lane + 4];
                    float4 t3 = *(const float4*)&bufE[2 * lane + 6];
                    float4 t4 = *(const float4*)&bufE[2 * lane + 8];
                    float4 t5 = *(const float4*)&bufE[2 * lane + 10];
                    v2f v[12];
                    v[0] = (v2f){t0.x, t0.y}; v[1] = (v2f){t0.z, t0.w};
                    v[2] = (v2f){t1.x, t1.y}; v[3] = (v2f){t1.z, t1.w};
                    v[4] = (v2f){t2.x, t2.y}; v[5] = (v2f){t2.z, t2.w};
                    v[6] = (v2f){t3.x, t3.y}; v[7] = (v2f){t3.z, t3.w};
                    v[8] = (v2f){t4.x, t4.y}; v[9] = (v2f){t4.z, t4.w};
                    v[10] = (v2f){t5.x, t5.y}; v[11] = (v2f){t5.z, t5.w};

                    v2f h01A = (v2f){0.f, 0.f}, h23A = (v2f){0.f, 0.f};
                    v2f h01B = (v2f){0.f, 0.f}, h23B = (v2f){0.f, 0.f};
                    float h4A = 0.f, h4B = 0.f;
#pragma unroll
                    for (int k = 0; k < FILT; k++) {
                        float w = gw.w[k];
                        v2f w2 = {w, w};
                        v2f va = v[k], vb = v[k + 1];
                        h01A = __builtin_elementwise_fma(w2, va, h01A);
                        h23A = __builtin_elementwise_fma(w2, va * va, h23A);
                        h4A = __builtin_fmaf(w, va.x * va.y, h4A);
                        h01B = __builtin_elementwise_fma(w2, vb, h01B);
                        h23B = __builtin_elementwise_fma(w2, vb * vb, h23B);
                        h4B = __builtin_fmaf(w, vb.x * vb.y, h4B);
                    }
#pragma unroll
                    for (int k = 0; k < FILT; k++) {
                        const int s = (pe - k + FILT) % FILT;
                        float w = gw.w[k];
                        v2f w2 = {w, w};
                        aA01[s] = __builtin_elementwise_fma(w2, h01A, aA01[s]);
                        aA23[s] = __builtin_elementwise_fma(w2, h23A, aA23[s]);
                        aA4[s] = __builtin_fmaf(w, h4A, aA4[s]);
                        aB01[s] = __builtin_elementwise_fma(w2, h01B, aB01[s]);
                        aB23[s] = __builtin_elementwise_fma(w2, h23B, aB23[s]);
                        aB4[s] = __builtin_fmaf(w, h4B, aB4[s]);
                    }
                    const int e = (pe + 1) % FILT;
                    if (r >= a + (FILT - 1)) {
                        if (colvA) {
                            float m1 = aA01[e].x, m2 = aA01[e].y;
                            float mu11 = m1 * m1, mu22 = m2 * m2, mu12 = m1 * m2;
                            float s1 = aA23[e].x - mu11, s2 = aA23[e].y - mu22;
                            float s12 = aA4[e] - mu12;
                            float A = 2.f * s12 + c2c, Bv = s1 + s2 + c2c;
                            float Cv = 2.f * mu12 + c1c, Dv = mu11 + mu22 + c1c;
                            float r_ = __builtin_amdgcn_rcpf(Bv * Dv);
                            lcs += A * Dv * r_;
                            lss += Cv * A * r_;
                        }
                        if (colvB) {
                            float m1 = aB01[e].x, m2 = aB01[e].y;
                            float mu11 = m1 * m1, mu22 = m2 * m2, mu12 = m1 * m2;
                            float s1 = aB23[e].x - mu11, s2 = aB23[e].y - mu22;
                            float s12 = aB4[e] - mu12;
                            float A = 2.f * s12 + c2c, Bv = s1 + s2 + c2c;
                            float Cv = 2.f * mu12 + c1c, Dv = mu11 + mu22 + c1c;
                            float r_ = __builtin_amdgcn_rcpf(Bv * Dv);
                            lcs += A * Dv * r_;
                            lss += Cv * A * r_;
                        }
                    }
                    aA01[e] = (v2f){0.f, 0.f}; aA23[e] = (v2f){0.f, 0.f}; aA4[e] = 0.f;
                    aB01[e] = (v2f){0.f, 0.f}; aB23[e] = (v2f){0.f, 0.f}; aB4[e] = 0.f;
                }

                // ======== row r+1 (odd, phase po) ========
                {
                    float4 t0 = *(const float4*)&bufO[2 * lane + 0];
                    float4 t1 = *(const float4*)&bufO[2 * lane + 2];
                    float4 t2 = *(const float4*)&bufO[2 * lane + 4];
                    float4 t3 = *(const float4*)&bufO[2 * lane + 6];
                    float4 t4 = *(const float4*)&bufO[2 * lane + 8];
                    float4 t5 = *(const float4*)&bufO[2 * lane + 10];
                    v2f v[12];
                    v[0] = (v2f){t0.x, t0.y}; v[1] = (v2f){t0.z, t0.w};
                    v[2] = (v2f){t1.x, t1.y}; v[3] = (v2f){t1.z, t1.w};
                    v[4] = (v2f){t2.x, t2.y}; v[5] = (v2f){t2.z, t2.w};
                    v[6] = (v2f){t3.x, t3.y}; v[7] = (v2f){t3.z, t3.w};
                    v[8] = (v2f){t4.x, t4.y}; v[9] = (v2f){t4.z, t4.w};
                    v[10] = (v2f){t5.x, t5.y}; v[11] = (v2f){t5.z, t5.w};

                    v2f h01A = (v2f){0.f, 0.f}, h23A = (v2f){0.f, 0.f};
                    v2f h01B = (v2f){0.f, 0.f}, h23B = (v2f){0.f, 0.f};
                    float h4A = 0.f, h4B = 0.f;
#pragma unroll
                    for (int k = 0; k < FILT; k++) {
                        float w = gw.w[k];
                        v2f w2 = {w, w};
                        v2f va = v[k], vb = v[k + 1];
                        h01A = __builtin_elementwise_fma(w2, va, h01A);
                        h23A = __builtin_elementwise_fma(w2, va * va, h23A);
                        h4A = __builtin_fmaf(w, va.x * va.y, h4A);
                        h01B = __builtin_elementwise_fma(w2, vb, h01B);
                        h23B = __builtin_elementwise_fma(w2, vb * vb, h23B);
                        h4B = __builtin_fmaf(w, vb.x * vb.y, h4B);
                    }
#pragma unroll
                    for (int k = 0; k < FILT; k++) {
                        const int s = (po - k + FILT) % FILT;
                        float w = gw.w[k];
                        v2f w2 = {w, w};
                        aA01[s] = __builtin_elementwise_fma(w2, h01A, aA01[s]);
                        aA23[s] = __builtin_elementwise_fma(w2, h23A, aA23[s]);
                        aA4[s] = __builtin_fmaf(w, h4A, aA4[s]);
                        aB01[s] = __builtin_elementwise_fma(w2, h01B, aB01[s]);
                        aB23[s] = __builtin_elementwise_fma(w2, h23B, aB23[s]);
                        aB4[s] = __builtin_fmaf(w, h4B, aB4[s]);
                    }
                    const int e = (po + 1) % FILT;
                    if (r >= a + (FILT - 1)) {
                        if (colvA) {
                            float m1 = aA01[e].x, m2 = aA01[e].y;
                            float mu11 = m1 * m1, mu22 = m2 * m2, mu12 = m1 * m2;
                            float s1 = aA23[e].x - mu11, s2 = aA23[e].y - mu22;
                            float s12 = aA4[e] - mu12;
                            float A = 2.f * s12 + c2c, Bv = s1 + s2 + c2c;
                            float Cv = 2.f * mu12 + c1c, Dv = mu11 + mu22 + c1c;
                            float r_ = __builtin_amdgcn_rcpf(Bv * Dv);
                            lcs += A * Dv * r_;
                            lss += Cv * A * r_;
                        }
                        if (colvB) {
                            float m1 = aB01[e].x, m2 = aB01[e].y;
                            float mu11 = m1 * m1, mu22 = m2 * m2, mu12 = m1 * m2;
                            float s1 = aB23[e].x - mu11, s2 = aB23[e].y - mu22;
                            float s12 = aB4[e] - mu12;
                            float A = 2.f * s12 + c2c, Bv = s1 + s2 + c2c;
                            float Cv = 2.f * mu12 + c1c, Dv = mu11 + mu22 + c1c;
                            float r_ = __builtin_amdgcn_rcpf(Bv * Dv);
                            lcs += A * Dv * r_;
                            lss += Cv * A * r_;
                        }
                    }
                    aA01[e] = (v2f){0.f, 0.f}; aA23[e] = (v2f){0.f, 0.f}; aA4[e] = 0.f;
                    aB01[e] = (v2f){0.f, 0.f}; aB23[e] = (v2f){0.f, 0.f}; aB4[e] = 0.f;
                }
            }
        }
    }

    for (int off = 32; off; off >>= 1) {
        lcs += __shfl_down(lcs, off);
        lss += __shfl_down(lss, off);
    }
    if (lane == 0) {
        atomicAdd(&cs_sum[n], lcs);
        atomicAdd(&ssim_sum[n], lss);
    }
}

// SSIM streaming over an LDS-resident tile (taps read directly; no staging).
__device__ __forceinline__ void ssim_lds_strip(
    const v2f* tile, int Wt, int Wo, int a, int out_hi, int lane,
    float c1c, float c2c, const GW& gw, float& lcs, float& lss)
{
    const int bEnd = out_hi + (FILT - 1);
    const int tl = min(lane, Wo - 1);
    const bool colv = lane < Wo;

    v2f acc01[FILT], acc23[FILT];
    float acc4[FILT];
#pragma unroll
    for (int s = 0; s < FILT; s++) {
        acc01[s] = (v2f){0.f, 0.f};
        acc23[s] = (v2f){0.f, 0.f};
        acc4[s] = 0.f;
    }

#pragma unroll 1
    for (int r0 = a; r0 < bEnd; r0 += FILT) {
#pragma unroll
        for (int p = 0; p < FILT; p++) {
            const int r = r0 + p;
            if (r < bEnd) {
                const v2f* row = tile + (size_t)r * Wt;
                v2f h01 = (v2f){0.f, 0.f}, h23 = (v2f){0.f, 0.f};
                float h4 = 0.f;
#pragma unroll
                for (int k = 0; k < FILT; k++) {
                    v2f v = row[tl + k];
                    float w = gw.w[k];
                    v2f w2 = {w, w};
                    h01 = __builtin_elementwise_fma(w2, v, h01);
                    v2f sq = v * v;
                    h23 = __builtin_elementwise_fma(w2, sq, h23);
                    h4 = __builtin_fmaf(w, v.x * v.y, h4);
                }
#pragma unroll
                for (int k = 0; k < FILT; k++) {
                    const int s = (p - k + FILT) % FILT;
                    float w = gw.w[k];
                    v2f w2 = {w, w};
                    acc01[s] = __builtin_elementwise_fma(w2, h01, acc01[s]);
                    acc23[s] = __builtin_elementwise_fma(w2, h23, acc23[s]);
                    acc4[s] = __builtin_fmaf(w, h4, acc4[s]);
                }
                const int e = (p + 1) % FILT;
                if (r >= a + (FILT - 1) && colv) {
                    float m1 = acc01[e].x, m2 = acc01[e].y;
                    float mu11 = m1 * m1, mu22 = m2 * m2, mu12 = m1 * m2;
                    float s1 = acc23[e].x - mu11;
                    float s2 = acc23[e].y - mu22;
                    float s12 = acc4[e] - mu12;
                    float A = 2.f * s12 + c2c, Bv = s1 + s2 + c2c;
                    float Cv = 2.f * mu12 + c1c, Dv = mu11 + mu22 + c1c;
                    float r_ = __builtin_amdgcn_rcpf(Bv * Dv);
                    lcs += A * Dv * r_;
                    lss += Cv * A * r_;
                }
                acc01[e] = (v2f){0.f, 0.f};
                acc23[e] = (v2f){0.f, 0.f};
                acc4[e] = 0.f;
            }
        }
    }
}

// Fused levels 2-4 + final reduction ("last block" pattern).
__global__ __launch_bounds__(1024) void ssim_tail(
    const float* __restrict__ x2, const float* __restrict__ y2,
    const unsigned* __restrict__ mm, float* __restrict__ ws2, GW gw,
    float* __restrict__ outp)
{
    __shared__ v2f ring[16][2][80];
    __shared__ v2f buf3[64 * 64];
    __shared__ v2f buf4[32 * 32];
    __shared__ int isLast;

    const int img = blockIdx.x;        // 0..95
    const int n = img / 3;
    const int wv = threadIdx.x >> 6;
    const int lane = threadIdx.x & 63;

    float* cs2 = ws2 + 2 + 2 * 32;
    float* cs3 = ws2 + 2 + 3 * 32;
    float* cs4 = ws2 + 2 + 4 * 32;
    float* ss2 = ws2 + 2 + 5 * 32 + 2 * 32;
    float* ss3 = ws2 + 2 + 5 * 32 + 3 * 32;
    float* ss4 = ws2 + 2 + 5 * 32 + 4 * 32;

    const float mv = dec_f(mm[0]) - dec_f(mm[1]);
    const float c1c = (0.01f * mv) * (0.01f * mv);
    const float c2c = (0.03f * mv) * (0.03f * mv);

    // ---------------- L2: stream from global, pool -> buf3 ----------------
    {
        const int strip = wv >> 3;          // 0..1
        const int band = wv & 7;            // 0..7
        const int H = 128, W = 128, Ho = 118, B = 16;
        const int a = band * B;
        const int out_hi = min(a + B, Ho);
        const int bEnd = out_hi + (FILT - 1);
        const int base = strip * 64;
        const float* xp = x2 + (size_t)img * H * W;
        const float* yp = y2 + (size_t)img * H * W;
        const int c0 = min(base + lane, W - 1);
        const int c1 = min(base + 64 + min(lane, 9), W - 1);
        const bool colv = (base + lane) < Ho;

        v2f* bufA = &ring[wv][0][0];
        v2f* bufB = &ring[wv][1][0];

        v2f acc01[FILT], acc23[FILT];
        float acc4[FILT];
#pragma unroll
        for (int s = 0; s < FILT; s++) {
            acc01[s] = (v2f){0.f, 0.f};
            acc23[s] = (v2f){0.f, 0.f};
            acc4[s] = 0.f;
        }
        float lcs = 0.f, lss = 0.f;

        const float* xr = xp + (size_t)a * W;
        const float* yr = yp + (size_t)a * W;
        float pfx0 = xr[c0], pfy0 = yr[c0];
        float pfx1 = xr[c1], pfy1 = yr[c1];

#pragma unroll 1
        for (int r0 = a; r0 < bEnd; r0 += FILT) {
#pragma unroll
            for (int p = 0; p < FILT; p++) {
                const int r = r0 + p;
                if (r < bEnd) {
                    v2f* bufc = (r & 1) ? bufB : bufA;
                    v2f* bufo = (r & 1) ? bufA : bufB;

                    bufc[lane] = (v2f){pfx0, pfy0};
                    if (lane < 10) bufc[64 + lane] = (v2f){pfx1, pfy1};

                    {
                        const int rn = min(r + 1, bEnd - 1);
                        const float* xn = xp + (size_t)rn * W;
                        const float* yn = yp + (size_t)rn * W;
                        pfx0 = xn[c0]; pfy0 = yn[c0];
                        pfx1 = xn[c1]; pfy1 = yn[c1];
                    }

                    v2f h01 = (v2f){0.f, 0.f}, h23 = (v2f){0.f, 0.f};
                    float h4 = 0.f;
#pragma unroll
                    for (int k = 0; k < FILT; k++) {
                        v2f v = bufc[lane + k];
                        float w = gw.w[k];
                        v2f w2 = {w, w};
                        h01 = __builtin_elementwise_fma(w2, v, h01);
                        v2f sq = v * v;
                        h23 = __builtin_elementwise_fma(w2, sq, h23);
                        h4 = __builtin_fmaf(w, v.x * v.y, h4);
                    }
#pragma unroll
                    for (int k = 0; k < FILT; k++) {
                        const int s = (p - k + FILT) % FILT;
                        float w = gw.w[k];
                        v2f w2 = {w, w};
                        acc01[s] = __builtin_elementwise_fma(w2, h01, acc01[s]);
                        acc23[s] = __builtin_elementwise_fma(w2, h23, acc23[s]);
                        acc4[s] = __builtin_fmaf(w, h4, acc4[s]);
                    }
                    const int e = (p + 1) % FILT;
                    if (r >= a + (FILT - 1) && colv) {
                        float m1 = acc01[e].x, m2 = acc01[e].y;
                        float mu11 = m1 * m1, mu22 = m2 * m2, mu12 = m1 * m2;
                        float s1 = acc23[e].x - mu11;
                        float s2 = acc23[e].y - mu22;
                        float s12 = acc4[e] - mu12;
                        float A = 2.f * s12 + c2c, Bv = s1 + s2 + c2c;
                        float Cv = 2.f * mu12 + c1c, Dv = mu11 + mu22 + c1c;
                        float r_ = __builtin_amdgcn_rcpf(Bv * Dv);
                        lcs += A * Dv * r_;
                        lss += Cv * A * r_;
                    }
                    acc01[e] = (v2f){0.f, 0.f};
                    acc23[e] = (v2f){0.f, 0.f};
                    acc4[e] = 0.f;

                    if ((r & 1) && r > a && lane < 32) {
                        const int pcl = (base >> 1) + lane;
                        const int pr = r >> 1;
                        v2f q00 = bufo[2 * lane];
                        v2f q01 = bufo[2 * lane + 1];
                        v2f q10 = bufc[2 * lane];
                        v2f q11 = bufc[2 * lane + 1];
                        buf3[pr * 64 + pcl] =
                            (q00 + q01 + q10 + q11) * (v2f){0.25f, 0.25f};
                    }
                }
            }
        }

        for (int off = 32; off; off >>= 1) {
            lcs += __shfl_down(lcs, off);
            lss += __shfl_down(lss, off);
        }
        if (lane == 0) {
            atomicAdd(&cs2[n], lcs);
            atomicAdd(&ss2[n], lss);
        }
    }
    __syncthreads();

    // ---------------- pool buf3 -> buf4 ----------------
    {
        const int pr = threadIdx.x >> 5;
        const int pcl = threadIdx.x & 31;
        v2f q = (buf3[(2 * pr) * 64 + 2 * pcl] + buf3[(2 * pr) * 64 + 2 * pcl + 1] +
                 buf3[(2 * pr + 1) * 64 + 2 * pcl] + buf3[(2 * pr + 1) * 64 + 2 * pcl + 1]) *
                (v2f){0.25f, 0.25f};
        buf4[pr * 32 + pcl] = q;
    }
    __syncthreads();

    // ---------------- L3 (waves 0-13) / L4 (waves 14-15) ------------------
    {
        float lcs = 0.f, lss = 0.f;
        bool isL3 = (wv < 14);
        if (isL3) {
            const int a = wv * 4;
            ssim_lds_strip(buf3, 64, 54, a, min(a + 4, 54), lane,
                           c1c, c2c, gw, lcs, lss);
        } else {
            const int a = (wv - 14) * 12;
            ssim_lds_strip(buf4, 32, 22, a, min(a + 12, 22), lane,
                           c1c, c2c, gw, lcs, lss);
        }
        for (int off = 32; off; off >>= 1) {
            lcs += __shfl_down(lcs, off);
            lss += __shfl_down(lss, off);
        }
        if (lane == 0) {
            atomicAdd(isL3 ? &cs3[n] : &cs4[n], lcs);
            atomicAdd(isL3 ? &ss3[n] : &ss4[n], lss);
        }
    }

    // ---------------- last-block final reduction ----------------
    __syncthreads();
    __threadfence();
    if (threadIdx.x == 0) {
        int old = atomicAdd((int*)(ws2 + 500), 1);
        isLast = (old == (int)gridDim.x - 1);
    }
    __syncthreads();
    if (isLast && threadIdx.x < 64) {
        const float cnt[5] = {3.f * 502 * 502, 3.f * 246 * 246, 3.f * 118 * 118,
                              3.f * 54 * 54, 3.f * 22 * 22};
        const float wts[5] = {0.0448f, 0.2856f, 0.3001f, 0.2363f, 0.1333f};
        int nn = threadIdx.x;
        float ms = 0.f;
        if (nn < 32) {
            float* cs = ws2 + 2;
            float* ss = ws2 + 2 + 5 * 32;
            float ssim = atomicAdd(&ss[4 * 32 + nn], 0.f) / cnt[4];
            float t = powf(ssim, wts[4]);
            ms = 1.f;
            for (int l = 0; l < 4; l++) {
                float cv = atomicAdd(&cs[l * 32 + nn], 0.f) / cnt[l];
                ms *= powf(cv, wts[l]) * t;  // faithful: ssim^w4 inside product
            }
        }
        for (int off = 32; off; off >>= 1) ms += __shfl_down(ms, off);
        if (threadIdx.x == 0) outp[0] = ms / 32.f;
    }
}

extern "C" void kernel_launch(void* const* d_in, const int* in_sizes, int n_in,
                              void* d_out, int out_size, void* d_ws, size_t ws_size,
                              hipStream_t stream) {
    const float* x0 = (const float*)d_in[0];
    const float* y0 = (const float*)d_in[1];
    float* out = (float*)d_out;
    float* ws = (float*)d_ws;
    unsigned* mm = (unsigned*)d_ws;
    float* cs_sum = ws + 2;
    float* ssim_sum = ws + 2 + 5 * 32;

    const int N = 32, C = 3, NC = N * C;

    // pyramid buffers: only levels 1 and 2 materialized
    float* wp = ws + 512;
    float* pxw1 = wp; wp += (size_t)NC * 256 * 256;
    float* pyw1 = wp; wp += (size_t)NC * 256 * 256;
    float* pxw2 = wp; wp += (size_t)NC * 128 * 128;
    float* pyw2 = wp; wp += (size_t)NC * 128 * 128;

    // gaussian weights (softmax of -c^2/(2*sigma^2))
    GW gw;
    {
        double tmp[FILT], s = 0.0;
        for (int k = 0; k < FILT; k++) {
            double c = (double)k - (FILT - 1) / 2.0;
            tmp[k] = exp(-c * c / (2.0 * 1.5 * 1.5));
            s += tmp[k];
        }
        for (int k = 0; k < FILT; k++) gw.w[k] = (float)(tmp[k] / s);
    }

    init_acc<<<1, 256, 0, stream>>>(mm);
    long n4 = (long)NC * 512 * 512 / 4;
    minmax_kernel<<<2048, 256, 0, stream>>>((const float4*)y0, n4, mm);

    // L0: 128-wide strips, 2 cols/lane
    {
        int H = 512, Ho = 502;
        int nstrips = (Ho + 127) / 128;             // 4
        int B = 64, nb = (Ho + B - 1) / B;          // 8
        int total = NC * nstrips * nb;              // 3072 waves
        int grid = (total + 3) / 4;                 // 768
        ssim_stream2<<<grid, 256, 0, stream>>>(
            x0, y0, H, H, NC, nstrips, nb, B, mm,
            cs_sum + 0 * 32, ssim_sum + 0 * 32, gw, pxw1, pyw1, 1);
    }
    // L1: 128-wide strips
    {
        int H = 256, Ho = 246;
        int nstrips = (Ho + 127) / 128;             // 2
        int B = 32, nb = (Ho + B - 1) / B;          // 8
        int total = NC * nstrips * nb;              // 1536 waves
        int grid = (total + 3) / 4;                 // 384
        ssim_stream2<<<grid, 256, 0, stream>>>(
            pxw1, pyw1, H, H, NC, nstrips, nb, B, mm,
            cs_sum + 1 * 32, ssim_sum + 1 * 32, gw, pxw2, pyw2, 1);
    }
    // L2+L3+L4 + final fused
    ssim_tail<<<NC, 1024, 0, stream>>>(pxw2, pyw2, mm, ws, gw, out);
}